// Round 3
// baseline (833.104 us; speedup 1.0000x reference)
//
#include <hip/hip_runtime.h>

constexpr int N_ENTITIES = 100000;
constexpr int N_USERS    = 50000;
constexpr int N_FACTORS  = 4;
constexpr int N_META     = 8;
constexpr int CHANNEL    = 64;
constexpr int N_EDGES    = 1600000;
constexpr int NNZ        = 1000000;
constexpr int N_REL      = 31;   // n_relations - 1

// ws layout (4B units):
//   [0)            ent_cnt   N_ENTITIES
//   [100000)       user_cnt  N_USERS
//   [150000)       ent_cur   N_ENTITIES
//   [250000)       user_cur  N_USERS
//   [300000)       edge_pl   N_EDGES   (tail | rel<<17)
//   [1900000)      nnz_col   NNZ
//   [2900000)      nnz_val   NNZ (float)
// total 3.9M * 4B = 15.6 MB

__device__ __forceinline__ float wave_reduce_sum(float v) {
    for (int off = 32; off > 0; off >>= 1)
        v += __shfl_xor(v, off, 64);
    return v;
}

__global__ void count_kernel(const int* __restrict__ head,
                             const int* __restrict__ mat_row,
                             int* __restrict__ ent_cnt,
                             int* __restrict__ user_cnt) {
    const int i0 = blockIdx.x * blockDim.x + threadIdx.x;
    const int stride = gridDim.x * blockDim.x;
    for (int e = i0; e < N_EDGES; e += stride)
        atomicAdd(&ent_cnt[head[e]], 1);
    for (int z = i0; z < NNZ; z += stride)
        atomicAdd(&user_cnt[mat_row[z]], 1);
}

// grid = 2 blocks of 1024: block0 scans entity counts, block1 user counts.
// Writes exclusive prefix into cur[]. After scatter, cur[i] = start_i + cnt_i.
__global__ void scan_kernel(const int* __restrict__ ent_cnt, int* __restrict__ ent_cur,
                            const int* __restrict__ user_cnt, int* __restrict__ user_cur) {
    const int* cnt = (blockIdx.x == 0) ? ent_cnt : user_cnt;
    int*       cur = (blockIdx.x == 0) ? ent_cur : user_cur;
    const int  n   = (blockIdx.x == 0) ? N_ENTITIES : N_USERS;
    __shared__ int partial[1024];
    const int per   = (n + 1023) >> 10;
    const int start = threadIdx.x * per;
    const int end   = min(start + per, n);
    int s = 0;
    for (int i = start; i < end; ++i) s += cnt[i];
    partial[threadIdx.x] = s;
    __syncthreads();
    for (int d = 1; d < 1024; d <<= 1) {
        int v = (threadIdx.x >= d) ? partial[threadIdx.x - d] : 0;
        __syncthreads();
        partial[threadIdx.x] += v;
        __syncthreads();
    }
    int base = (threadIdx.x == 0) ? 0 : partial[threadIdx.x - 1];
    for (int i = start; i < end; ++i) {
        cur[i] = base;
        base += cnt[i];
    }
}

__global__ void scatter_kernel(const int* __restrict__ head,
                               const int* __restrict__ tail,
                               const int* __restrict__ etype,
                               const int* __restrict__ mat_row,
                               const int* __restrict__ mat_col,
                               const float* __restrict__ mat_val,
                               int* __restrict__ ent_cur,
                               int* __restrict__ user_cur,
                               int* __restrict__ edge_pl,
                               int* __restrict__ nnz_col,
                               float* __restrict__ nnz_val) {
    const int i0 = blockIdx.x * blockDim.x + threadIdx.x;
    const int stride = gridDim.x * blockDim.x;
    for (int e = i0; e < N_EDGES; e += stride) {
        const int h = head[e];
        const int pos = atomicAdd(&ent_cur[h], 1);
        edge_pl[pos] = tail[e] | ((etype[e] - 1) << 17);
    }
    for (int z = i0; z < NNZ; z += stride) {
        const int r = mat_row[z];
        const int pos = atomicAdd(&user_cur[r], 1);
        nnz_col[pos] = mat_col[z];
        nnz_val[pos] = mat_val[z];
    }
}

// One wave per entity: registers accumulate, single non-atomic row write,
// scatter-mean divide folded in.
__global__ void ent_agg_kernel(const float* __restrict__ entity_emb,
                               const float* __restrict__ rel_w,
                               const int* __restrict__ ent_cnt,
                               const int* __restrict__ ent_cur,
                               const int* __restrict__ edge_pl,
                               float* __restrict__ out_ent) {
    __shared__ float rw_s[N_REL][CHANNEL];   // 7.9 KB
    const int tid = threadIdx.x;
    for (int i = tid; i < N_REL * CHANNEL; i += blockDim.x)
        rw_s[i >> 6][i & 63] = rel_w[i];
    __syncthreads();

    const int lane = tid & 63;
    const int wib  = tid >> 6;
    const int wpb  = blockDim.x >> 6;
    for (int h = blockIdx.x * wpb + wib; h < N_ENTITIES; h += gridDim.x * wpb) {
        const int cnt   = ent_cnt[h];
        const int end   = ent_cur[h];       // = start + cnt after scatter
        const int start = end - cnt;
        const float eh  = entity_emb[h * CHANNEL + lane];
        float acc = 0.0f;
        for (int i = start; i < end; ++i) {
            const int pl = edge_pl[i];
            const int t  = pl & 0x1FFFF;
            const int r  = pl >> 17;
            const float rw = rw_s[r][lane];
            const float d  = wave_reduce_sum(eh * rw);
            const float att = 1.0f / (1.0f + __expf(-d));
            acc += att * rw * entity_emb[t * CHANNEL + lane];
        }
        out_ent[h * CHANNEL + lane] = acc / fmaxf((float)cnt, 1.0f);
    }
}

// One wave per user: SpMM segment accumulate + gating epilogue fused.
__global__ void user_agg_kernel(const float* __restrict__ entity_emb,
                                const float* __restrict__ user_emb,
                                const float* __restrict__ latent_emb, // (4,64)
                                const float* __restrict__ weight,     // (8,64)
                                const float* __restrict__ datt,       // (4,8)
                                const int* __restrict__ user_cnt,
                                const int* __restrict__ user_cur,
                                const int* __restrict__ nnz_col,
                                const float* __restrict__ nnz_val,
                                float* __restrict__ out_user) {
    __shared__ float dw[N_FACTORS][CHANNEL];
    const int tid = threadIdx.x;
    if (tid < N_FACTORS * CHANNEL) {   // blockDim >= 256
        const int f = tid >> 6, c = tid & 63;
        float m = -1e30f;
        for (int j = 0; j < N_META; ++j) m = fmaxf(m, datt[f * N_META + j]);
        float p[N_META]; float s = 0.0f;
        for (int j = 0; j < N_META; ++j) { p[j] = __expf(datt[f * N_META + j] - m); s += p[j]; }
        const float invs = 1.0f / s;
        float acc = 0.0f;
        for (int j = 0; j < N_META; ++j) acc += p[j] * invs * weight[j * CHANNEL + c];
        dw[f][c] = acc;
    }
    __syncthreads();

    const int lane = tid & 63;
    const int wib  = tid >> 6;
    const int wpb  = blockDim.x >> 6;
    for (int u = blockIdx.x * wpb + wib; u < N_USERS; u += gridDim.x * wpb) {
        const int cnt   = user_cnt[u];
        const int end   = user_cur[u];
        const int start = end - cnt;
        float acc = 0.0f;
        for (int i = start; i < end; ++i) {
            const int c   = nnz_col[i];
            const float v = nnz_val[i];
            acc += v * entity_emb[c * CHANNEL + lane];
        }
        const float ue = user_emb[u * CHANNEL + lane];
        float d0 = wave_reduce_sum(ue * latent_emb[0 * CHANNEL + lane]);
        float d1 = wave_reduce_sum(ue * latent_emb[1 * CHANNEL + lane]);
        float d2 = wave_reduce_sum(ue * latent_emb[2 * CHANNEL + lane]);
        float d3 = wave_reduce_sum(ue * latent_emb[3 * CHANNEL + lane]);
        const float m = fmaxf(fmaxf(d0, d1), fmaxf(d2, d3));
        d0 = __expf(d0 - m); d1 = __expf(d1 - m);
        d2 = __expf(d2 - m); d3 = __expf(d3 - m);
        const float invs = 1.0f / (d0 + d1 + d2 + d3);
        const float g = (d0 * dw[0][lane] + d1 * dw[1][lane] +
                         d2 * dw[2][lane] + d3 * dw[3][lane]) * invs;
        out_user[u * CHANNEL + lane] = acc * (1.0f + g);
    }
}

extern "C" void kernel_launch(void* const* d_in, const int* in_sizes, int n_in,
                              void* d_out, int out_size, void* d_ws, size_t ws_size,
                              hipStream_t stream) {
    const float* entity_emb = (const float*)d_in[0];
    const float* user_emb   = (const float*)d_in[1];
    const float* latent_emb = (const float*)d_in[2];
    const int*   head       = (const int*)d_in[3];
    const int*   tail       = (const int*)d_in[4];
    const int*   etype      = (const int*)d_in[5];
    const int*   mat_row    = (const int*)d_in[6];
    const int*   mat_col    = (const int*)d_in[7];
    const float* mat_val    = (const float*)d_in[8];
    const float* rel_w      = (const float*)d_in[9];
    const float* weight     = (const float*)d_in[10];
    const float* datt       = (const float*)d_in[11];

    float* out      = (float*)d_out;
    float* out_ent  = out;                                  // N_ENTITIES*64
    float* out_user = out + (size_t)N_ENTITIES * CHANNEL;   // N_USERS*64

    int*   ws       = (int*)d_ws;
    int*   ent_cnt  = ws;                 // 100000
    int*   user_cnt = ws + 100000;        // 50000
    int*   ent_cur  = ws + 150000;        // 100000
    int*   user_cur = ws + 250000;        // 50000
    int*   edge_pl  = ws + 300000;        // 1600000
    int*   nnz_col  = ws + 1900000;       // 1000000
    float* nnz_val  = (float*)(ws + 2900000); // 1000000

    // zero only the count arrays (ent_cnt + user_cnt contiguous)
    hipMemsetAsync(ent_cnt, 0, 150000 * sizeof(int), stream);

    count_kernel<<<2048, 256, 0, stream>>>(head, mat_row, ent_cnt, user_cnt);
    scan_kernel<<<2, 1024, 0, stream>>>(ent_cnt, ent_cur, user_cnt, user_cur);
    scatter_kernel<<<2048, 256, 0, stream>>>(head, tail, etype, mat_row, mat_col,
                                             mat_val, ent_cur, user_cur,
                                             edge_pl, nnz_col, nnz_val);
    ent_agg_kernel<<<4096, 256, 0, stream>>>(entity_emb, rel_w, ent_cnt, ent_cur,
                                             edge_pl, out_ent);
    user_agg_kernel<<<2048, 256, 0, stream>>>(entity_emb, user_emb, latent_emb,
                                              weight, datt, user_cnt, user_cur,
                                              nnz_col, nnz_val, out_user);
}